// Round 3
// baseline (421.780 us; speedup 1.0000x reference)
//
#include <hip/hip_runtime.h>
#include <math.h>

#define NEGV  (-1e30f)
#define LOG2E 1.4426950408889634f
#define LN2f  0.6931471805599453f

__device__ __forceinline__ float fexp2(float x) {
    float r; asm("v_exp_f32 %0, %1" : "=v"(r) : "v"(x)); return r;
}
__device__ __forceinline__ float flog2(float x) {
    float r; asm("v_log_f32 %0, %1" : "=v"(r) : "v"(x)); return r;
}
// log-add-exp in base-2 domain (inputs/outputs pre-scaled by log2e)
__device__ __forceinline__ float lae2_2(float a, float b) {
    float m = fmaxf(a, b);
    return m + flog2(fexp2(a - m) + fexp2(b - m));
}
__device__ __forceinline__ float lae3_2(float a, float b, float c) {
    float m = fmaxf(fmaxf(a, b), c);
    return m + flog2(fexp2(a - m) + fexp2(b - m) + fexp2(c - m));
}

// One wave (64 lanes) per (sample, sequence). Lane owns extended positions
// s = 4*lane .. 4*lane+3 (L = 201 <= 256). Alpha lives in registers; the only
// cross-lane traffic is prev-lane a3 via ds_bpermute (even positions are
// blanks -> no skip -> the s-2 neighbor is never needed across lanes).
// Class rows staged global->LDS with one global_load_lds dwordx4 per row,
// 16-deep ring, counted vmcnt(14) per step (loads stay in flight).
__global__ __launch_bounds__(64) void ctc_scan_kernel(
    const float* __restrict__ lp,        // (T, N, C) log-probs
    const int* __restrict__ labels,      // (N, S)
    const int* __restrict__ rlabels,     // (N, S)
    const int* __restrict__ ilen,        // (N,)
    const int* __restrict__ llenp,       // (N,)
    const int* __restrict__ rlenp,       // (N,)
    float* __restrict__ loss,            // (2N,)
    int T, int N, int C, int S)
{
    const int n    = blockIdx.x >> 1;
    const int sq   = blockIdx.x & 1;
    const int lane = threadIdx.x;
    const int L    = 2 * S + 1;

    const int* lab = sq ? rlabels : labels;
    const int  ll  = sq ? rlenp[n] : llenp[n];
    const int  inlen = ilen[n];

    __shared__ float ring[16][256];      // 16 KiB row ring
    __shared__ float aout[256];

    // per-lane extended labels / skip flags for odd positions s = 4*lane+{1,3}
    int e1i = 0, e3i = 0;
    bool k1 = false, k3 = false;
    {
        const int s1 = 4 * lane + 1;
        if (s1 < L) {
            int j = s1 >> 1;
            e1i = lab[n * S + j];
            if (s1 >= 3) k1 = (e1i != lab[n * S + j - 1]);  // labels>=1 so !=blank
        }
        const int s3 = 4 * lane + 3;
        if (s3 < L) {
            int j = s3 >> 1;
            e3i = lab[n * S + j];
            k3 = (e3i != lab[n * S + j - 1]);               // s3 >= 3 always
        }
    }

    const size_t rowstride = (size_t)N * C;
    const float* gbase = lp + (size_t)n * C + lane * 4;     // per-lane 16B slot
    const int Tm1 = T - 1;

    auto issue_row = [&](int row) {
        int r = row < Tm1 ? row : Tm1;                      // clamp (keeps vmcnt math uniform)
        const float* src = gbase + (size_t)r * rowstride;
        __builtin_amdgcn_global_load_lds(
            (const __attribute__((address_space(1))) char*)src,
            (__attribute__((address_space(3))) char*)&ring[row & 15][0],
            16, 0, 0);                                      // 64 lanes x 16B = whole row
    };

    for (int r = 0; r < 16; ++r) issue_row(r);

    const int bpaddr = (lane > 0 ? lane - 1 : 0) << 2;      // ds_bpermute byte addr

    asm volatile("s_waitcnt vmcnt(15)" ::: "memory");       // row 0 complete
    float em0 = ring[0][0]   * LOG2E;                       // blank emit (both even pos)
    float em1 = ring[0][e1i] * LOG2E;
    float em3 = ring[0][e3i] * LOG2E;

    // t = 0 init: only s=0 (blank) and s=1 (first label) reachable
    float a0 = (lane == 0) ? em0 : NEGV;
    float a1 = (lane == 0) ? em1 : NEGV;
    float a2 = NEGV, a3 = NEGV;

    asm volatile("s_waitcnt vmcnt(14)" ::: "memory");       // row 1 complete
    {
        const float* r1 = &ring[1][0];
        em0 = r1[0]   * LOG2E;
        em1 = r1[e1i] * LOG2E;
        em3 = r1[e3i] * LOG2E;
    }

    for (int t = 1; t < T; ++t) {
        issue_row(t + 15);                                  // slot (t-1)&15, row t-1 dead
        asm volatile("s_waitcnt vmcnt(14)" ::: "memory");   // row t+1 complete
        // prefetch next step's emits now; latency hides under the lae chain
        const float* rn = &ring[(t + 1) & 15][0];
        float em0n = rn[0]   * LOG2E;
        float em1n = rn[e1i] * LOG2E;
        float em3n = rn[e3i] * LOG2E;

        int shf = __builtin_amdgcn_ds_bpermute(bpaddr, __float_as_int(a3));

        // all updates read OLD alphas; order puts non-shuffle ones first
        float v3 = lae3_2(a3, a2, k3 ? a1 : NEGV) + em3;
        float v2 = lae2_2(a2, a1) + em0;
        float pA3 = (lane == 0) ? NEGV : __int_as_float(shf);
        float v1 = lae3_2(a1, a0, k1 ? pA3 : NEGV) + em1;
        float v0 = lae2_2(a0, pA3) + em0;

        if (t < inlen) { a0 = v0; a1 = v1; a2 = v2; a3 = v3; }  // freeze past length
        em0 = em0n; em1 = em1n; em3 = em3n;
    }

    reinterpret_cast<float4*>(aout)[lane] = make_float4(a0, a1, a2, a3);
    __syncthreads();
    if (lane == 0) {
        float hi = aout[2 * ll];
        float lo = aout[2 * ll - 1];
        loss[sq * N + n] = -lae2_2(hi, lo) * LN2f;          // back to base-e
    }
}

__global__ __launch_bounds__(256) void ctc_finalize_kernel(
    const float* __restrict__ ws, float* __restrict__ out, int N)
{
    __shared__ float sc[256], sh[256];
    const int i = threadIdx.x;
    float c = 0.f, h = 0.f;
    for (int nn = i; nn < N; nn += 256) {
        float cv = ws[nn];
        float rv = ws[N + nn];
        c += cv;
        float dap = fabsf(1e-6f - cv);
        float dan = fabsf(1e-6f - rv);
        h += fmaxf(dap - dan + 16.0f, 0.f);
    }
    sc[i] = c; sh[i] = h;
    __syncthreads();
    for (int off = 128; off > 0; off >>= 1) {
        if (i < off) { sc[i] += sc[i + off]; sh[i] += sh[i + off]; }
        __syncthreads();
    }
    if (i == 0) out[0] = sc[0] + sh[0] / (float)N;
}

extern "C" void kernel_launch(void* const* d_in, const int* in_sizes, int n_in,
                              void* d_out, int out_size, void* d_ws, size_t ws_size,
                              hipStream_t stream) {
    const float* lp      = (const float*)d_in[0];   // predicts (T,N,C) f32
    const int* labels    = (const int*)d_in[1];     // (N,S)
    const int* rlabels   = (const int*)d_in[2];     // (N,S)
    const int* plen      = (const int*)d_in[3];     // (N,)
    const int* llen      = (const int*)d_in[4];     // (N,)
    const int* rlen      = (const int*)d_in[5];     // (N,)

    const int N = in_sizes[3];
    const int S = in_sizes[1] / N;
    const int C = 256;
    const int T = in_sizes[0] / (N * C);

    float* ws = (float*)d_ws;                       // 2N floats of per-seq losses

    ctc_scan_kernel<<<2 * N, 64, 0, stream>>>(lp, labels, rlabels, plen, llen, rlen,
                                              ws, T, N, C, S);
    ctc_finalize_kernel<<<1, 256, 0, stream>>>(ws, (float*)d_out, N);
}

// Round 5
// 115.648 us; speedup vs baseline: 3.6471x; 3.6471x over previous
//
#include <hip/hip_runtime.h>
#include <math.h>

#define LOG2E 1.4426950408889634f
#define LN2F  0.6931471805599453f
#define NEGB  (-1e30f)

__device__ __forceinline__ float fexp2(float x){ float r; asm("v_exp_f32 %0, %1":"=v"(r):"v"(x)); return r; }
__device__ __forceinline__ float flog2(float x){ float r; asm("v_log_f32 %0, %1":"=v"(r):"v"(x)); return r; }

// DPP helper: invalid source lanes produce 0 (old=0).
template<int CTRL>
__device__ __forceinline__ float dppf(float x){
    return __int_as_float(__builtin_amdgcn_update_dpp(0, __float_as_int(x), CTRL, 0xf, 0xf, false));
}

// One wave per (sample, sequence). Lane owns extended positions 4l..4l+3.
// Alpha in LINEAR probability domain, wave-uniform scale 2^E (exact), rescaled
// every 6 steps via DPP wave-max. Positions beyond the sample's true extended
// length 2*ll are held at exactly 0 (emit masked to 0) so they can never
// dominate the rescale max. Neighbor alpha[4l-1] via DPP row_shr:1 +
// row_bcast15 — pure VALU, no LDS in the hot loop. Emits gathered from global
// into a 4-bank x 3-step register pipeline (static indices only).
__global__ __launch_bounds__(64) void ctc_scan_kernel(
    const float* __restrict__ lp,        // (T, N, C) log-probs
    const int* __restrict__ labels,      // (N, S)
    const int* __restrict__ rlabels,     // (N, S)
    const int* __restrict__ ilen,        // (N,)
    const int* __restrict__ llen,        // (N,)
    const int* __restrict__ rlen,        // (N,)
    float* __restrict__ loss,            // (2N,)
    int T, int N, int C, int S)
{
    const int n    = blockIdx.x >> 1;
    const int sq   = blockIdx.x & 1;
    const int lane = threadIdx.x;

    const int* lab = sq ? rlabels : labels;
    const int  ll  = sq ? rlen[n] : llen[n];
    int Teff = ilen[n]; if (Teff > T) Teff = T;
    const int Tm1 = T - 1;

    // labels for odd positions s=4l+1 (j0=2l), s=4l+3 (j1=2l+1)
    int e1 = 0, e3 = 0;
    bool k1 = false, k3 = false;
    {
        int j0 = 2*lane, j1 = 2*lane + 1;
        if (j0 < S){ e1 = lab[n*S + j0]; if (j0 > 0) k1 = (e1 != lab[n*S + j0 - 1]); }
        if (j1 < S){ e3 = lab[n*S + j1]; k3 = (e3 != e1); }
    }
    // validity: position s is real iff s <= 2*ll  (labels: j < ll)
    const float m0 = (2*lane     <= ll) ? 1.f : 0.f;   // s=4l   (blank)
    const float m2 = (2*lane + 1 <= ll) ? 1.f : 0.f;   // s=4l+2 (blank)
    const float b1 = (2*lane     <  ll) ? 0.f : NEGB;  // s=4l+1 (label 2l)
    const float b3 = (2*lane + 1 <  ll) ? 0.f : NEGB;  // s=4l+3 (label 2l+1)
    const bool bnd = ((lane & 15) == 0) && (lane != 0);  // lanes 16,32,48

    const size_t NC = (size_t)N * C;
    const float* base = lp + (size_t)n * C;

    // t=0 init (linear): only s=0 (blank) and s=1 (label0) reachable
    float a0, a1, a2 = 0.f, a3 = 0.f;
    {
        float pb0 = fexp2(base[0]  * LOG2E);
        float p10 = fexp2(base[e1] * LOG2E);
        a0 = (lane == 0) ? pb0 : 0.f;
        a1 = (lane == 0) ? p10 : 0.f;
    }
    int E = 0;   // true alpha = a * 2^E

    // register pipeline: 4 banks x 3 steps of pre-scaled (base-2) log emits;
    // invalid odd positions carry -1e30 -> exp2 -> 0.
    float Rb[4][3], Rx[4][3], Ry[4][3];
#pragma unroll
    for (int q = 0; q < 4; ++q)
#pragma unroll
        for (int u = 0; u < 3; ++u){
            int tt = 1 + q*3 + u; tt = tt < T ? tt : Tm1;
            const float* rp = base + (size_t)tt * NC;
            Rb[q][u] = rp[0] * LOG2E;
            Rx[q][u] = fmaf(rp[e1], LOG2E, b1);
            Ry[q][u] = fmaf(rp[e3], LOG2E, b3);
        }

    auto stepf = [&](float PB, float PX, float PY){
        float pb = fexp2(PB);
        float p1 = fexp2(PX);
        float p3 = fexp2(PY);
        float sh = dppf<0x111>(a3);            // row_shr:1 (lanes 0/16/32/48 -> 0)
        float bc = dppf<0x142>(a3);            // row_bcast15
        float pa3 = bnd ? bc : sh;             // prev-lane a3; lane0 -> 0
        float v0 = (a0 + pa3) * (pb * m0);
        float v1 = (a1 + a0 + (k1 ? pa3 : 0.f)) * p1;
        float v2 = (a2 + a1) * (pb * m2);
        float v3 = (a3 + a2 + (k3 ? a1 : 0.f)) * p3;
        a0 = v0; a1 = v1; a2 = v2; a3 = v3;
    };

    auto rescale = [&](){
        float m = fmaxf(fmaxf(a0, a1), fmaxf(a2, a3));
        m = fmaxf(m, dppf<0x111>(m));          // row inclusive-max chain
        m = fmaxf(m, dppf<0x112>(m));
        m = fmaxf(m, dppf<0x114>(m));
        m = fmaxf(m, dppf<0x118>(m));
        m = fmaxf(m, dppf<0x142>(m));          // cross-row combine
        m = fmaxf(m, dppf<0x143>(m));          // lane63 = wave max
        float wmax = __int_as_float(__builtin_amdgcn_readlane(__float_as_int(m), 63));
        int ex = ((__float_as_int(wmax) >> 23) & 255) - 127;  // floor(log2)
        a0 = ldexpf(a0, -ex); a1 = ldexpf(a1, -ex);
        a2 = ldexpf(a2, -ex); a3 = ldexpf(a3, -ex);
        E += ex;                                // exact power-of-2 bookkeeping
    };

    int t = 1;
    for (; t + 12 <= Teff; t += 12){
#pragma unroll
        for (int q = 0; q < 4; ++q){
#pragma unroll
            for (int u = 0; u < 3; ++u) stepf(Rb[q][u], Rx[q][u], Ry[q][u]);
            // refill bank q with rows t+12+q*3+u (used 9-12 steps later)
#pragma unroll
            for (int u = 0; u < 3; ++u){
                int tt = t + 12 + q*3 + u; tt = tt < T ? tt : Tm1;
                const float* rp = base + (size_t)tt * NC;
                Rb[q][u] = rp[0] * LOG2E;
                Rx[q][u] = fmaf(rp[e1], LOG2E, b1);
                Ry[q][u] = fmaf(rp[e3], LOG2E, b3);
            }
            if (q & 1) rescale();               // every 6 steps
        }
    }
    // tail (<12 steps): banks hold rows t..t+11
#pragma unroll
    for (int i = 0; i < 12; ++i){
        if (t + i < Teff) stepf(Rb[i/3][i%3], Rx[i/3][i%3], Ry[i/3][i%3]);
    }

    __shared__ __align__(16) float aout[256];
    reinterpret_cast<float4*>(aout)[lane] = make_float4(a0, a1, a2, a3);
    __syncthreads();
    if (lane == 0){
        float hi = aout[2*ll], lo = aout[2*ll - 1];
        loss[sq * N + n] = -(flog2(hi + lo) + (float)E) * LN2F;
    }
}

__global__ __launch_bounds__(256) void ctc_finalize_kernel(
    const float* __restrict__ ws, float* __restrict__ out, int N)
{
    __shared__ float sc[256], sh[256];
    const int i = threadIdx.x;
    float c = 0.f, h = 0.f;
    for (int nn = i; nn < N; nn += 256) {
        float cv = ws[nn];
        float rv = ws[N + nn];
        c += cv;
        float dap = fabsf(1e-6f - cv);
        float dan = fabsf(1e-6f - rv);
        h += fmaxf(dap - dan + 16.0f, 0.f);
    }
    sc[i] = c; sh[i] = h;
    __syncthreads();
    for (int off = 128; off > 0; off >>= 1) {
        if (i < off) { sc[i] += sc[i + off]; sh[i] += sh[i + off]; }
        __syncthreads();
    }
    if (i == 0) out[0] = sc[0] + sh[0] / (float)N;
}

extern "C" void kernel_launch(void* const* d_in, const int* in_sizes, int n_in,
                              void* d_out, int out_size, void* d_ws, size_t ws_size,
                              hipStream_t stream) {
    const float* lp      = (const float*)d_in[0];   // predicts (T,N,C) f32
    const int* labels    = (const int*)d_in[1];     // (N,S)
    const int* rlabels   = (const int*)d_in[2];     // (N,S)
    const int* plen      = (const int*)d_in[3];     // (N,)
    const int* llen      = (const int*)d_in[4];     // (N,)
    const int* rlen      = (const int*)d_in[5];     // (N,)

    const int N = in_sizes[3];
    const int S = in_sizes[1] / N;
    const int C = 256;
    const int T = in_sizes[0] / (N * C);

    float* ws = (float*)d_ws;                       // 2N floats of per-seq losses

    ctc_scan_kernel<<<2 * N, 64, 0, stream>>>(lp, labels, rlabels, plen, llen, rlen,
                                              ws, T, N, C, S);
    ctc_finalize_kernel<<<1, 256, 0, stream>>>(ws, (float*)d_out, N);
}

// Round 6
// 102.188 us; speedup vs baseline: 4.1275x; 1.1317x over previous
//
#include <hip/hip_runtime.h>
#include <math.h>

#define LOG2E 1.4426950408889634f
#define LN2F  0.6931471805599453f
#define NEGB  (-1e30f)

__device__ __forceinline__ float fexp2(float x){ float r; asm("v_exp_f32 %0, %1":"=v"(r):"v"(x)); return r; }
__device__ __forceinline__ float flog2(float x){ float r; asm("v_log_f32 %0, %1":"=v"(r):"v"(x)); return r; }

// DPP helper: invalid source lanes produce 0 (old=0, bound_ctrl off).
template<int CTRL>
__device__ __forceinline__ float dppf(float x){
    return __int_as_float(__builtin_amdgcn_update_dpp(0, __float_as_int(x), CTRL, 0xf, 0xf, false));
}

// Pinned gather load: asm volatile cannot be sunk/rematerialized by the
// compiler, so the 54-deep in-flight pipeline actually exists. Consumption is
// ordered by explicit counted s_waitcnt vmcnt(N) + sched_barrier(0).
__device__ __forceinline__ float gload(const float* sbase, int voff){
    float r;
    asm volatile("global_load_dword %0, %1, %2"
                 : "=v"(r) : "v"(voff), "s"(sbase));
    return r;
}

#define WAITV(N) asm volatile("s_waitcnt vmcnt(" #N ")" ::: "memory")
#define SB0() __builtin_amdgcn_sched_barrier(0)

// One wave per (sample, sequence). Lane owns extended positions 4l..4l+3.
// Alpha in LINEAR probability domain, wave-uniform scale 2^E (exact), rescaled
// every 6 steps via DPP wave-max. Positions beyond 2*label_len are held at
// exactly 0 (emit masked) so they never dominate the rescale max. Neighbor
// alpha[4l-1] via DPP row_shr:1 + row_bcast15 — no LDS in the hot loop.
// Emits stream global->register through an 18-row (54-load) asm pipeline with
// counted vmcnt(45) per 3-row group.
__global__ __launch_bounds__(64) void ctc_scan_kernel(
    const float* __restrict__ lp,        // (T, N, C) log-probs
    const int* __restrict__ labels,      // (N, S)
    const int* __restrict__ rlabels,     // (N, S)
    const int* __restrict__ ilen,        // (N,)
    const int* __restrict__ llen,        // (N,)
    const int* __restrict__ rlen,        // (N,)
    float* __restrict__ loss,            // (2N,)
    int T, int N, int C, int S)
{
    const int n    = blockIdx.x >> 1;
    const int sq   = blockIdx.x & 1;
    const int lane = threadIdx.x;

    const int* lab = sq ? rlabels : labels;
    const int  ll  = sq ? rlen[n] : llen[n];
    int Teff = ilen[n]; if (Teff > T) Teff = T;
    const int Tm1 = T - 1;

    // labels for odd positions s=4l+1 (j0=2l), s=4l+3 (j1=2l+1)
    int e1 = 0, e3 = 0;
    bool k1 = false, k3 = false;
    {
        int j0 = 2*lane, j1 = 2*lane + 1;
        if (j0 < S){ e1 = lab[n*S + j0]; if (j0 > 0) k1 = (e1 != lab[n*S + j0 - 1]); }
        if (j1 < S){ e3 = lab[n*S + j1]; k3 = (e3 != e1); }
    }
    // validity: position s is real iff s <= 2*ll
    const float m0 = (2*lane     <= ll) ? 1.f : 0.f;   // s=4l   (blank)
    const float m2 = (2*lane + 1 <= ll) ? 1.f : 0.f;   // s=4l+2 (blank)
    const float b1 = (2*lane     <  ll) ? 0.f : NEGB;  // s=4l+1
    const float b3 = (2*lane + 1 <  ll) ? 0.f : NEGB;  // s=4l+3
    const bool bnd = ((lane & 15) == 0) && (lane != 0);  // lanes 16,32,48

    const size_t NC = (size_t)N * C;
    const float* base = lp + (size_t)n * C;
    const int vx = 4*e1, vy = 4*e3, vz = 0;

    // t=0 init (normal loads; drained before the asm pipeline starts)
    float a0, a1, a2 = 0.f, a3 = 0.f;
    {
        float pb0 = fexp2(base[0]  * LOG2E);
        float p10 = fexp2(base[e1] * LOG2E);
        a0 = (lane == 0) ? pb0 : 0.f;
        a1 = (lane == 0) ? p10 : 0.f;
    }
    int E = 0;   // true alpha = a * 2^E

    asm volatile("s_waitcnt vmcnt(0)" ::: "memory");   // drain prologue loads
    SB0();

    // issue the 18-row pipeline: rows 1..18, order (B,X,Y) per row
    float Rb[6][3], Rx[6][3], Ry[6][3];
#pragma unroll
    for (int g = 0; g < 6; ++g)
#pragma unroll
        for (int u = 0; u < 3; ++u){
            int row = 1 + g*3 + u; if (row > Tm1) row = Tm1;
            const float* rp = base + (size_t)row * NC;
            Rb[g][u] = gload(rp, vz);
            Rx[g][u] = gload(rp, vx);
            Ry[g][u] = gload(rp, vy);
        }

    auto stepf = [&](float PB, float PX, float PY){
        float pb = fexp2(PB * LOG2E);
        float p1 = fexp2(fmaf(PX, LOG2E, b1));     // invalid -> exp2(-1e30) = 0
        float p3 = fexp2(fmaf(PY, LOG2E, b3));
        float sh = dppf<0x111>(a3);                // row_shr:1 (lanes 0/16/32/48 -> 0)
        float bc = dppf<0x142>(a3);                // row_bcast15
        float pa3 = bnd ? bc : sh;                 // prev-lane a3; lane0 -> 0
        float v0 = (a0 + pa3) * (pb * m0);
        float v1 = (a1 + a0 + (k1 ? pa3 : 0.f)) * p1;
        float v2 = (a2 + a1) * (pb * m2);
        float v3 = (a3 + a2 + (k3 ? a1 : 0.f)) * p3;
        a0 = v0; a1 = v1; a2 = v2; a3 = v3;
    };

    auto rescale = [&](){
        float m = fmaxf(fmaxf(a0, a1), fmaxf(a2, a3));
        m = fmaxf(m, dppf<0x111>(m));
        m = fmaxf(m, dppf<0x112>(m));
        m = fmaxf(m, dppf<0x114>(m));
        m = fmaxf(m, dppf<0x118>(m));
        m = fmaxf(m, dppf<0x142>(m));
        m = fmaxf(m, dppf<0x143>(m));              // lane63 = wave max
        float wmax = __int_as_float(__builtin_amdgcn_readlane(__float_as_int(m), 63));
        int ex = ((__float_as_int(wmax) >> 23) & 255) - 127;
        a0 = ldexpf(a0, -ex); a1 = ldexpf(a1, -ex);
        a2 = ldexpf(a2, -ex); a3 = ldexpf(a3, -ex);
        E += ex;
    };

    int t = 1;
    for (; t + 18 <= Teff; t += 18){
#pragma unroll
        for (int g = 0; g < 6; ++g){
            WAITV(45);                              // oldest 9 (this group's rows) done
            SB0();                                  // nothing moves above the wait
            stepf(Rb[g][0], Rx[g][0], Ry[g][0]);
            stepf(Rb[g][1], Rx[g][1], Ry[g][1]);
            stepf(Rb[g][2], Rx[g][2], Ry[g][2]);
            if (g & 1) rescale();                   // every 6 steps
            // refill bank g with rows t+18+3g+u (consumed next outer iter)
#pragma unroll
            for (int u = 0; u < 3; ++u){
                int row = t + 18 + g*3 + u; if (row > Tm1) row = Tm1;
                const float* rp = base + (size_t)row * NC;
                Rb[g][u] = gload(rp, vz);
                Rx[g][u] = gload(rp, vx);
                Ry[g][u] = gload(rp, vy);
            }
        }
    }

    // tail (<18 steps): banks hold rows t..t+17
    WAITV(0);
    SB0();
#pragma unroll
    for (int g = 0; g < 6; ++g){
#pragma unroll
        for (int u = 0; u < 3; ++u)
            if (t + g*3 + u < Teff) stepf(Rb[g][u], Rx[g][u], Ry[g][u]);
        if (t + g*3 < Teff) rescale();              // keep alphas in fp32 range
    }

    __shared__ __align__(16) float aout[256];
    reinterpret_cast<float4*>(aout)[lane] = make_float4(a0, a1, a2, a3);
    __syncthreads();
    if (lane == 0){
        float hi = aout[2*ll], lo = aout[2*ll - 1];
        loss[sq * N + n] = -(flog2(hi + lo) + (float)E) * LN2F;
    }
}

__global__ __launch_bounds__(256) void ctc_finalize_kernel(
    const float* __restrict__ ws, float* __restrict__ out, int N)
{
    __shared__ float sc[256], sh[256];
    const int i = threadIdx.x;
    float c = 0.f, h = 0.f;
    for (int nn = i; nn < N; nn += 256) {
        float cv = ws[nn];
        float rv = ws[N + nn];
        c += cv;
        float dap = fabsf(1e-6f - cv);
        float dan = fabsf(1e-6f - rv);
        h += fmaxf(dap - dan + 16.0f, 0.f);
    }
    sc[i] = c; sh[i] = h;
    __syncthreads();
    for (int off = 128; off > 0; off >>= 1) {
        if (i < off) { sc[i] += sc[i + off]; sh[i] += sh[i + off]; }
        __syncthreads();
    }
    if (i == 0) out[0] = sc[0] + sh[0] / (float)N;
}

extern "C" void kernel_launch(void* const* d_in, const int* in_sizes, int n_in,
                              void* d_out, int out_size, void* d_ws, size_t ws_size,
                              hipStream_t stream) {
    const float* lp      = (const float*)d_in[0];   // predicts (T,N,C) f32
    const int* labels    = (const int*)d_in[1];     // (N,S)
    const int* rlabels   = (const int*)d_in[2];     // (N,S)
    const int* plen      = (const int*)d_in[3];     // (N,)
    const int* llen      = (const int*)d_in[4];     // (N,)
    const int* rlen      = (const int*)d_in[5];     // (N,)

    const int N = in_sizes[3];
    const int S = in_sizes[1] / N;
    const int C = 256;
    const int T = in_sizes[0] / (N * C);

    float* ws = (float*)d_ws;                       // 2N floats of per-seq losses

    ctc_scan_kernel<<<2 * N, 64, 0, stream>>>(lp, labels, rlabels, plen, llen, rlen,
                                              ws, T, N, C, S);
    ctc_finalize_kernel<<<1, 256, 0, stream>>>(ws, (float*)d_out, N);
}